// Round 9
// baseline (311.725 us; speedup 1.0000x reference)
//
#include <hip/hip_runtime.h>
#include <hip/hip_bf16.h>

// B=2, S=2048, D_MODEL=1024, H=16, D_HEAD=64.
// I/O fp32; mask int32 (nonzero = masked). Internals bf16 MFMA.
// R8 post-mortem: attn 88.5us (LDS staging win). Residual ~215us = GEMM
// scalar-store epilogue. R9: LDS-transpose epilogue -> coalesced 16B stores.

typedef __bf16 bf16x8 __attribute__((ext_vector_type(8)));
typedef float f32x4 __attribute__((ext_vector_type(4)));

#define S_LEN 2048
#define DM 1024
#define NH 16
#define DH 64
#define MROWS 4096  // B*S

static __device__ __forceinline__ unsigned short f2bf(float f) {
    __hip_bfloat16 h = __float2bfloat16(f);
    unsigned short u; __builtin_memcpy(&u, &h, 2); return u;
}

static __device__ __forceinline__ bf16x8 cvt8(float4 a, float4 b) {
    bf16x8 o;
    o[0] = (__bf16)a.x; o[1] = (__bf16)a.y; o[2] = (__bf16)a.z; o[3] = (__bf16)a.w;
    o[4] = (__bf16)b.x; o[5] = (__bf16)b.y; o[6] = (__bf16)b.z; o[7] = (__bf16)b.w;
    return o;
}

// fp32 -> bf16 for up to 4 tensors (same n), blockIdx.y selects.
__global__ __launch_bounds__(256)
void cvt4(const float* __restrict__ s0, unsigned short* __restrict__ d0,
          const float* __restrict__ s1, unsigned short* __restrict__ d1,
          const float* __restrict__ s2, unsigned short* __restrict__ d2,
          const float* __restrict__ s3, unsigned short* __restrict__ d3, int n)
{
    const float* s = blockIdx.y == 0 ? s0 : blockIdx.y == 1 ? s1 : blockIdx.y == 2 ? s2 : s3;
    unsigned short* d = blockIdx.y == 0 ? d0 : blockIdx.y == 1 ? d1 : blockIdx.y == 2 ? d2 : d3;
    int i = (blockIdx.x * 256 + threadIdx.x) * 8;
    if (i < n) {
        float4 a = *(const float4*)(s + i);
        float4 b = *(const float4*)(s + i + 4);
        *(bf16x8*)(d + i) = cvt8(a, b);
    }
}

// mask int32 [B*S][S] -> bit-packed [B*S][S/32]
__global__ __launch_bounds__(256)
void pack_mask(const int* __restrict__ m, unsigned* __restrict__ mb)
{
    const int lane = threadIdx.x & 63, w = threadIdx.x >> 6;
    const int row = blockIdx.x * 4 + w;
    const int* src = m + (size_t)row * S_LEN;
    unsigned* dst = mb + (size_t)row * (S_LEN / 32);
    for (int i = 0; i < 32; i++) {
        int v = src[i * 64 + lane];
        unsigned long long bm = __ballot(v != 0);
        if (lane == 0) { dst[i * 2] = (unsigned)bm; dst[i * 2 + 1] = (unsigned)(bm >> 32); }
    }
}

// m97-style GEMM: Y = X @ W^T + bias, 128x128 tile, BK=32, global_load_lds,
// LDS-transpose epilogue (coalesced 16B stores).
__global__ __launch_bounds__(256)
void gemm128(const unsigned short* __restrict__ X0, const unsigned short* __restrict__ X1,
             const unsigned short* __restrict__ X2,
             const unsigned short* __restrict__ W0, const unsigned short* __restrict__ W1,
             const unsigned short* __restrict__ W2,
             const float* __restrict__ b0, const float* __restrict__ b1,
             const float* __restrict__ b2,
             unsigned short* __restrict__ d0, unsigned short* __restrict__ d1,
             unsigned short* __restrict__ d2, float* __restrict__ dstf, int mode_base)
{
    __shared__ __align__(16) unsigned short As[128 * 32];  // unpadded: global_load_lds order
    __shared__ __align__(16) unsigned short Bs[128 * 32];
    __shared__ __align__(16) float Ep[4][16 * 68];          // per-wave epilogue buffer
    const int z = blockIdx.z;
    const unsigned short* X = z == 0 ? X0 : z == 1 ? X1 : X2;
    const unsigned short* W = z == 0 ? W0 : z == 1 ? W1 : W2;
    const float* bias        = z == 0 ? b0 : z == 1 ? b1 : b2;
    unsigned short* dstb     = z == 0 ? d0 : z == 1 ? d1 : d2;
    const int mode = mode_base + z;

    const int tid  = threadIdx.x;
    const int m0   = blockIdx.y * 128;
    const int n0   = blockIdx.x * 128;
    const int lane = tid & 63;
    const int w    = tid >> 6;
    const int wm   = (w >> 1) * 64, wn = (w & 1) * 64;
    const int lr   = lane & 15;
    const int lg   = lane >> 4;

    f32x4 acc[4][4];
#pragma unroll
    for (int i = 0; i < 4; i++)
#pragma unroll
        for (int j = 0; j < 4; j++) acc[i][j] = f32x4{0.f, 0.f, 0.f, 0.f};

    for (int k0 = 0; k0 < DM; k0 += 32) {
        __syncthreads();
#pragma unroll
        for (int j = 0; j < 2; j++) {
            int e = tid + j * 256;                 // 0..511 -> 128 rows x 32 cols
            int row = e >> 2, c8 = (e & 3) * 8;
            __builtin_amdgcn_global_load_lds(
                (const __attribute__((address_space(1))) unsigned*)&X[(size_t)(m0 + row) * DM + k0 + c8],
                (__attribute__((address_space(3))) unsigned*)&As[e * 8], 16, 0, 0);
            __builtin_amdgcn_global_load_lds(
                (const __attribute__((address_space(1))) unsigned*)&W[(size_t)(n0 + row) * DM + k0 + c8],
                (__attribute__((address_space(3))) unsigned*)&Bs[e * 8], 16, 0, 0);
        }
        __syncthreads();
        bf16x8 af[4], bfr[4];
#pragma unroll
        for (int mi = 0; mi < 4; mi++)
            af[mi] = *(const bf16x8*)(&As[(wm + mi * 16 + lr) * 32 + lg * 8]);
#pragma unroll
        for (int ni = 0; ni < 4; ni++)
            bfr[ni] = *(const bf16x8*)(&Bs[(wn + ni * 16 + lr) * 32 + lg * 8]);
#pragma unroll
        for (int mi = 0; mi < 4; mi++)
#pragma unroll
            for (int ni = 0; ni < 4; ni++)
                acc[mi][ni] = __builtin_amdgcn_mfma_f32_16x16x32_bf16(
                    af[mi], bfr[ni], acc[mi][ni], 0, 0, 0);
    }

    // C/D layout: col = lane&15, row = (lane>>4)*4 + reg.
    // Epilogue: per mi-slice, LDS-transpose to emit coalesced 16B stores.
    // Wave covers cols n0+wn..+64 -> one h for modes 0/1 (h = (n0+wn)>>6).
    const float bv = bias[n0 + wn + ((mode == 2) ? lr : 0) + ((mode == 2) ? 0 : 0)];
    (void)bv;
#pragma unroll
    for (int mi = 0; mi < 4; mi++) {
        if (mode == 2) {
#pragma unroll
            for (int ni = 0; ni < 4; ni++) {
                const int gcol = n0 + wn + ni * 16 + lr;
                const float bb = bias[gcol];
                const int grow0 = m0 + wm + mi * 16 + lg * 4;
                int b = grow0 >> 11, s = grow0 & (S_LEN - 1);
                int h = gcol >> 6, dh = gcol & 63;
                unsigned short us[4];
#pragma unroll
                for (int r = 0; r < 4; r++) us[r] = f2bf(acc[mi][ni][r] + bb);
                size_t di = ((size_t)(b * NH + h) * DH + dh) * S_LEN + s;
                unsigned lo = (unsigned)us[0] | ((unsigned)us[1] << 16);
                unsigned hi = (unsigned)us[2] | ((unsigned)us[3] << 16);
                *(uint2*)(&dstb[di]) = uint2{lo, hi};
            }
        } else if (mode == 3) {
            // fp32: stage [16][64] (+4 pad) floats, read back coalesced.
            float* ep = &Ep[w][0];
#pragma unroll
            for (int ni = 0; ni < 4; ni++) {
                const float bb = bias[n0 + wn + ni * 16 + lr];
#pragma unroll
                for (int r = 0; r < 4; r++)
                    ep[(lg * 4 + r) * 68 + ni * 16 + lr] = acc[mi][ni][r] + bb;
            }
            int row = lane >> 2;
            int grow = m0 + wm + mi * 16 + row;
            float* dst = &dstf[(size_t)grow * DM + n0 + wn];
#pragma unroll
            for (int j = 0; j < 4; j++) {
                int seg = (lane & 3) + j * 4;           // 16 segs of 4 floats
                float4 v = *(const float4*)(&ep[row * 68 + seg * 4]);
                *(float4*)(&dst[seg * 4]) = v;
            }
        } else {
            // bf16 head-split: stage [16][64] (+8 pad) shorts, coalesced 16B.
            unsigned short* ep = (unsigned short*)&Ep[w][0];
#pragma unroll
            for (int ni = 0; ni < 4; ni++) {
                const float bb = bias[n0 + wn + ni * 16 + lr];
#pragma unroll
                for (int r = 0; r < 4; r++)
                    ep[(lg * 4 + r) * 72 + ni * 16 + lr] = f2bf(acc[mi][ni][r] + bb);
            }
            int row = lane >> 2;
            int grow = m0 + wm + mi * 16 + row;
            int b = grow >> 11, s = grow & (S_LEN - 1);
            int h = (n0 + wn) >> 6;
            unsigned short* dst = &dstb[((size_t)(b * NH + h) * S_LEN + s) * DH];
#pragma unroll
            for (int j = 0; j < 2; j++) {
                int seg = (lane & 3) + j * 4;           // 8 segs of 8 shorts
                bf16x8 v = *(const bf16x8*)(&ep[row * 72 + seg * 8]);
                *(bf16x8*)(&dst[seg * 8]) = v;
            }
        }
    }
}

// Flash attention: cooperative LDS staging of K/V tiles, full kv loop,
// constant-shift softmax, ctx bf16 written directly.
// Grid 1024 (1D, XCD swizzle: 4 bh per XCD). 4 waves, 16 q-rows/wave.
__global__ __launch_bounds__(256, 4)
void attn(const unsigned short* __restrict__ q_ws,
          const unsigned short* __restrict__ k_ws,
          const unsigned short* __restrict__ vt_ws,
          const unsigned* __restrict__ mbits,
          unsigned short* __restrict__ ctx)
{
    __shared__ __align__(16) unsigned short Ks[64 * 72];  // [kv][dh], +8 pad
    __shared__ __align__(16) unsigned short Vs[64 * 72];  // [dh][kv], +8 pad
    __shared__ __align__(16) unsigned short P_lds[4][16 * 72];
    const int tid = threadIdx.x, lane = tid & 63, w = tid >> 6;
    const int lr = lane & 15, lg = lane >> 4;

    const int i    = blockIdx.x;            // 0..1023
    const int xcd  = i & 7;
    const int slot = i >> 3;                // 0..127
    const int bh   = xcd * 4 + (slot >> 5); // 4 bh per XCD
    const int qblk = slot & 31;
    const int b  = bh >> 4;
    const int h  = bh & 15;
    const int q0 = qblk * 64 + w * 16;

    const int srow = tid >> 3;   // 0..31 (staging row)
    const int sseg = tid & 7;    // 0..7  (16B segment)

    const unsigned short* qh = q_ws + (size_t)bh * S_LEN * DH;
    const unsigned short* kh = k_ws + (size_t)bh * S_LEN * DH;
    const unsigned short* vh = vt_ws + (size_t)bh * DH * S_LEN;
    const unsigned* mrow = mbits + (size_t)(b * S_LEN) * (S_LEN / 32);

    bf16x8 aq[2];
#pragma unroll
    for (int c = 0; c < 2; c++)
        aq[c] = *(const bf16x8*)(&qh[(size_t)(q0 + lr) * DH + c * 32 + lg * 8]);

    f32x4 acc[4];
#pragma unroll
    for (int di = 0; di < 4; di++) acc[di] = f32x4{0.f, 0.f, 0.f, 0.f};
    float rs[4] = {0.f, 0.f, 0.f, 0.f};

    // Prefetch tile 0 into regs.
    uint4 kreg0, kreg1, vreg0, vreg1;
    kreg0 = *(const uint4*)(&kh[(size_t)(srow)      * DH + sseg * 8]);
    kreg1 = *(const uint4*)(&kh[(size_t)(srow + 32) * DH + sseg * 8]);
    vreg0 = *(const uint4*)(&vh[(size_t)(srow)      * S_LEN + sseg * 8]);
    vreg1 = *(const uint4*)(&vh[(size_t)(srow + 32) * S_LEN + sseg * 8]);

    for (int it = 0; it < 32; it++) {
        const int kv0 = it * 64;
        __syncthreads();   // previous tile fully consumed
        *(uint4*)(&Ks[(srow)      * 72 + sseg * 8]) = kreg0;
        *(uint4*)(&Ks[(srow + 32) * 72 + sseg * 8]) = kreg1;
        *(uint4*)(&Vs[(srow)      * 72 + sseg * 8]) = vreg0;
        *(uint4*)(&Vs[(srow + 32) * 72 + sseg * 8]) = vreg1;
        __syncthreads();   // tile ready
        if (it < 31) {     // prefetch next tile (overlaps compute below)
            const int kn = kv0 + 64;
            kreg0 = *(const uint4*)(&kh[(size_t)(kn + srow)      * DH + sseg * 8]);
            kreg1 = *(const uint4*)(&kh[(size_t)(kn + srow + 32) * DH + sseg * 8]);
            vreg0 = *(const uint4*)(&vh[(size_t)(srow)      * S_LEN + kn + sseg * 8]);
            vreg1 = *(const uint4*)(&vh[(size_t)(srow + 32) * S_LEN + kn + sseg * 8]);
        }

        uint2 mw[4];
#pragma unroll
        for (int r = 0; r < 4; r++)
            mw[r] = *(const uint2*)(&mrow[(size_t)(q0 + lg * 4 + r) * (S_LEN / 32) + (kv0 >> 5)]);

        f32x4 sf[4];
#pragma unroll
        for (int ni = 0; ni < 4; ni++) {
            bf16x8 bk0 = *(const bf16x8*)(&Ks[(ni * 16 + lr) * 72 + lg * 8]);
            bf16x8 bk1 = *(const bf16x8*)(&Ks[(ni * 16 + lr) * 72 + 32 + lg * 8]);
            f32x4 t = __builtin_amdgcn_mfma_f32_16x16x32_bf16(aq[0], bk0, f32x4{0.f,0.f,0.f,0.f}, 0,0,0);
            t = __builtin_amdgcn_mfma_f32_16x16x32_bf16(aq[1], bk1, t, 0,0,0);
            sf[ni] = t;
        }
#pragma unroll
        for (int ni = 0; ni < 4; ni++)
#pragma unroll
            for (int r = 0; r < 4; r++) {
                unsigned word = (ni & 2) ? mw[r].y : mw[r].x;
                unsigned bit = (word >> ((ni & 1) * 16 + lr)) & 1u;
                float t = sf[ni][r] * 0.125f + (bit ? -1e5f : -8.0f);
                float p = __expf(fminf(t, 60.f));
                sf[ni][r] = p;
                rs[r] += p;
            }

        // P (C-layout) -> LDS -> A-layout fragments. Per-wave region.
        unsigned short* pl_ = &P_lds[w][0];
#pragma unroll
        for (int ni = 0; ni < 4; ni++)
#pragma unroll
            for (int r = 0; r < 4; r++)
                pl_[(lg * 4 + r) * 72 + ni * 16 + lr] = f2bf(sf[ni][r]);

        bf16x8 ap0 = *(const bf16x8*)(&pl_[lr * 72 + lg * 8]);
        bf16x8 ap1 = *(const bf16x8*)(&pl_[lr * 72 + 32 + lg * 8]);
#pragma unroll
        for (int di = 0; di < 4; di++) {
            bf16x8 bv0 = *(const bf16x8*)(&Vs[(di * 16 + lr) * 72 + lg * 8]);
            bf16x8 bv1 = *(const bf16x8*)(&Vs[(di * 16 + lr) * 72 + 32 + lg * 8]);
            acc[di] = __builtin_amdgcn_mfma_f32_16x16x32_bf16(ap0, bv0, acc[di], 0, 0, 0);
            acc[di] = __builtin_amdgcn_mfma_f32_16x16x32_bf16(ap1, bv1, acc[di], 0, 0, 0);
        }
    }

    // Row sums -> normalize -> ctx bf16 [b*S+q][h*64+dh].
    float inv[4];
#pragma unroll
    for (int r = 0; r < 4; r++) {
        float v = rs[r];
        v += __shfl_xor(v, 1);
        v += __shfl_xor(v, 2);
        v += __shfl_xor(v, 4);
        v += __shfl_xor(v, 8);
        inv[r] = 1.0f / fmaxf(v, 1e-37f);
    }
#pragma unroll
    for (int di = 0; di < 4; di++)
#pragma unroll
        for (int r = 0; r < 4; r++) {
            int qrow = q0 + lg * 4 + r;
            ctx[((size_t)(b * S_LEN + qrow)) * DM + h * DH + di * 16 + lr] =
                f2bf(acc[di][r] * inv[r]);
        }
}

extern "C" void kernel_launch(void* const* d_in, const int* in_sizes, int n_in,
                              void* d_out, int out_size, void* d_ws, size_t ws_size,
                              hipStream_t stream)
{
    (void)in_sizes; (void)n_in; (void)out_size; (void)ws_size;
    const float* Q  = (const float*)d_in[0];
    const float* K  = (const float*)d_in[1];
    const float* V  = (const float*)d_in[2];
    const int*   Mk = (const int*)d_in[3];
    const float* Wq = (const float*)d_in[4];
    const float* bq = (const float*)d_in[5];
    const float* Wk = (const float*)d_in[6];
    const float* bk = (const float*)d_in[7];
    const float* Wv = (const float*)d_in[8];
    const float* bv = (const float*)d_in[9];
    const float* Wo = (const float*)d_in[10];
    const float* bo = (const float*)d_in[11];

    const int NX = MROWS * DM;   // 4194304
    const int NW = DM * DM;      // 1048576

    unsigned short* q_ws  = (unsigned short*)d_ws;
    unsigned short* k_ws  = q_ws + (size_t)NX;
    unsigned short* vt_ws = k_ws + (size_t)NX;
    unsigned short* ctx   = vt_ws + (size_t)NX;
    unsigned*       mbits = (unsigned*)(ctx + (size_t)NX);
    unsigned short* Wbq   = (unsigned short*)(mbits + (size_t)MROWS * (S_LEN / 32));
    unsigned short* Wbk   = Wbq + (size_t)NW;
    unsigned short* Wbv   = Wbk + (size_t)NW;
    unsigned short* Wbo   = Wbv + (size_t)NW;
    unsigned short* Xbq   = Wbo + (size_t)NW;
    unsigned short* Xbk   = Xbq + (size_t)NX;
    unsigned short* Xbv   = Xbk + (size_t)NX;
    float* out = (float*)d_out;

    dim3 blk(256);
    pack_mask<<<dim3(1024), blk, 0, stream>>>(Mk, mbits);
    cvt4<<<dim3(2048, 3), blk, 0, stream>>>(Q, Xbq, K, Xbk, V, Xbv,
                                            nullptr, nullptr, NX);
    cvt4<<<dim3(512, 4), blk, 0, stream>>>(Wq, Wbq, Wk, Wbk, Wv, Wbv, Wo, Wbo, NW);

    gemm128<<<dim3(8, 32, 3), blk, 0, stream>>>(Xbq, Xbk, Xbv, Wbq, Wbk, Wbv,
                                                bq, bk, bv, q_ws, k_ws, vt_ws,
                                                nullptr, 0);

    attn<<<dim3(1024), blk, 0, stream>>>(q_ws, k_ws, vt_ws, mbits, ctx);

    gemm128<<<dim3(8, 32, 1), blk, 0, stream>>>(ctx, nullptr, nullptr, Wbo, nullptr, nullptr,
                                                bo, nullptr, nullptr, nullptr, nullptr, nullptr,
                                                out, 3);
}

// Round 10
// 280.857 us; speedup vs baseline: 1.1099x; 1.1099x over previous
//
#include <hip/hip_runtime.h>
#include <hip/hip_bf16.h>

// B=2, S=2048, D_MODEL=1024, H=16, D_HEAD=64.
// I/O fp32; mask int32 (nonzero = masked). Internals bf16 MFMA.
// R9 post-mortem: epilogue LDS-transpose regressed -> reverted. R10:
// transposed attention (S^T = K*Q^T, softmax along lanes) to cut LDS/VALU/mask
// traffic; out-proj at 2 blocks/CU; single fused prep kernel.

typedef __bf16 bf16x8 __attribute__((ext_vector_type(8)));
typedef float f32x4 __attribute__((ext_vector_type(4)));

#define S_LEN 2048
#define DM 1024
#define NH 16
#define DH 64
#define MROWS 4096  // B*S

static __device__ __forceinline__ unsigned short f2bf(float f) {
    __hip_bfloat16 h = __float2bfloat16(f);
    unsigned short u; __builtin_memcpy(&u, &h, 2); return u;
}

static __device__ __forceinline__ bf16x8 cvt8(float4 a, float4 b) {
    bf16x8 o;
    o[0] = (__bf16)a.x; o[1] = (__bf16)a.y; o[2] = (__bf16)a.z; o[3] = (__bf16)a.w;
    o[4] = (__bf16)b.x; o[5] = (__bf16)b.y; o[6] = (__bf16)b.z; o[7] = (__bf16)b.w;
    return o;
}

// Fused prep: mask bit-pack + 3 X cvts + 4 W cvts in one launch.
// Grid 9216 x 256: [0,1024) mask rows, [1024,7168) X, [7168,9216) W.
__global__ __launch_bounds__(256)
void prep(const int* __restrict__ m, unsigned* __restrict__ mb,
          const float* __restrict__ Q, unsigned short* __restrict__ dQ,
          const float* __restrict__ K, unsigned short* __restrict__ dK,
          const float* __restrict__ V, unsigned short* __restrict__ dV,
          const float* __restrict__ W0, unsigned short* __restrict__ dW0,
          const float* __restrict__ W1, unsigned short* __restrict__ dW1,
          const float* __restrict__ W2, unsigned short* __restrict__ dW2,
          const float* __restrict__ W3, unsigned short* __restrict__ dW3)
{
    const int bx = blockIdx.x, tid = threadIdx.x;
    if (bx < 1024) {
        const int lane = tid & 63, w = tid >> 6;
        const int row = bx * 4 + w;
        const int* src = m + (size_t)row * S_LEN;
        unsigned* dst = mb + (size_t)row * (S_LEN / 32);
        for (int i = 0; i < 32; i++) {
            int v = src[i * 64 + lane];
            unsigned long long bm = __ballot(v != 0);
            if (lane == 0) { dst[i*2] = (unsigned)bm; dst[i*2+1] = (unsigned)(bm >> 32); }
        }
    } else if (bx < 7168) {
        int t = bx - 1024;
        int which = t >> 11;
        const float* s = which == 0 ? Q : which == 1 ? K : V;
        unsigned short* d = which == 0 ? dQ : which == 1 ? dK : dV;
        int i = ((t & 2047) * 256 + tid) * 8;
        float4 a = *(const float4*)(s + i);
        float4 b = *(const float4*)(s + i + 4);
        *(bf16x8*)(d + i) = cvt8(a, b);
    } else {
        int t = bx - 7168;
        int which = t >> 9;
        const float* s = which == 0 ? W0 : which == 1 ? W1 : which == 2 ? W2 : W3;
        unsigned short* d = which == 0 ? dW0 : which == 1 ? dW1 : which == 2 ? dW2 : dW3;
        int i = ((t & 511) * 256 + tid) * 8;
        float4 a = *(const float4*)(s + i);
        float4 b = *(const float4*)(s + i + 4);
        *(bf16x8*)(d + i) = cvt8(a, b);
    }
}

// m97-style GEMM for QKV: 128x128 tile, BK=32, global_load_lds. z = mode:
// 0/1: head-split bf16 (q_ws/k_ws); 2: transposed bf16 (vt_ws).
__global__ __launch_bounds__(256)
void gemm128(const unsigned short* __restrict__ X0, const unsigned short* __restrict__ X1,
             const unsigned short* __restrict__ X2,
             const unsigned short* __restrict__ W0, const unsigned short* __restrict__ W1,
             const unsigned short* __restrict__ W2,
             const float* __restrict__ b0, const float* __restrict__ b1,
             const float* __restrict__ b2,
             unsigned short* __restrict__ d0, unsigned short* __restrict__ d1,
             unsigned short* __restrict__ d2)
{
    __shared__ __align__(16) unsigned short As[128 * 32];
    __shared__ __align__(16) unsigned short Bs[128 * 32];
    const int z = blockIdx.z;
    const unsigned short* X = z == 0 ? X0 : z == 1 ? X1 : X2;
    const unsigned short* W = z == 0 ? W0 : z == 1 ? W1 : W2;
    const float* bias        = z == 0 ? b0 : z == 1 ? b1 : b2;
    unsigned short* dstb     = z == 0 ? d0 : z == 1 ? d1 : d2;

    const int tid  = threadIdx.x;
    const int m0   = blockIdx.y * 128;
    const int n0   = blockIdx.x * 128;
    const int lane = tid & 63;
    const int w    = tid >> 6;
    const int wm   = (w >> 1) * 64, wn = (w & 1) * 64;
    const int lr   = lane & 15;
    const int lg   = lane >> 4;

    f32x4 acc[4][4];
#pragma unroll
    for (int i = 0; i < 4; i++)
#pragma unroll
        for (int j = 0; j < 4; j++) acc[i][j] = f32x4{0.f, 0.f, 0.f, 0.f};

    for (int k0 = 0; k0 < DM; k0 += 32) {
        __syncthreads();
#pragma unroll
        for (int j = 0; j < 2; j++) {
            int e = tid + j * 256;
            int row = e >> 2, c8 = (e & 3) * 8;
            __builtin_amdgcn_global_load_lds(
                (const __attribute__((address_space(1))) unsigned*)&X[(size_t)(m0 + row) * DM + k0 + c8],
                (__attribute__((address_space(3))) unsigned*)&As[e * 8], 16, 0, 0);
            __builtin_amdgcn_global_load_lds(
                (const __attribute__((address_space(1))) unsigned*)&W[(size_t)(n0 + row) * DM + k0 + c8],
                (__attribute__((address_space(3))) unsigned*)&Bs[e * 8], 16, 0, 0);
        }
        __syncthreads();
        bf16x8 af[4], bfr[4];
#pragma unroll
        for (int mi = 0; mi < 4; mi++)
            af[mi] = *(const bf16x8*)(&As[(wm + mi * 16 + lr) * 32 + lg * 8]);
#pragma unroll
        for (int ni = 0; ni < 4; ni++)
            bfr[ni] = *(const bf16x8*)(&Bs[(wn + ni * 16 + lr) * 32 + lg * 8]);
#pragma unroll
        for (int mi = 0; mi < 4; mi++)
#pragma unroll
            for (int ni = 0; ni < 4; ni++)
                acc[mi][ni] = __builtin_amdgcn_mfma_f32_16x16x32_bf16(
                    af[mi], bfr[ni], acc[mi][ni], 0, 0, 0);
    }

    // C/D layout: col = lane&15, row = (lane>>4)*4 + reg. (R8 epilogue)
#pragma unroll
    for (int mi = 0; mi < 4; mi++) {
#pragma unroll
        for (int ni = 0; ni < 4; ni++) {
            const int gcol = n0 + wn + ni * 16 + lr;
            const float bv = bias[gcol];
            const int grow0 = m0 + wm + mi * 16 + lg * 4;
            if (z == 2) {
                int b = grow0 >> 11, s = grow0 & (S_LEN - 1);
                int h = gcol >> 6, dh = gcol & 63;
                unsigned short us[4];
#pragma unroll
                for (int r = 0; r < 4; r++) us[r] = f2bf(acc[mi][ni][r] + bv);
                size_t di = ((size_t)(b * NH + h) * DH + dh) * S_LEN + s;
                unsigned lo = (unsigned)us[0] | ((unsigned)us[1] << 16);
                unsigned hi = (unsigned)us[2] | ((unsigned)us[3] << 16);
                *(uint2*)(&dstb[di]) = uint2{lo, hi};
            } else {
#pragma unroll
                for (int r = 0; r < 4; r++) {
                    int grow = grow0 + r;
                    float v = acc[mi][ni][r] + bv;
                    int b = grow >> 11, s = grow & (S_LEN - 1);
                    int h = gcol >> 6, dh = gcol & 63;
                    dstb[((size_t)(b * NH + h) * S_LEN + s) * DH + dh] = f2bf(v);
                }
            }
        }
    }
}

// Out-projection: Y = X @ Wo^T + bo, fp32 out. 128M x 64N tiles, grid (16,32)
// = 512 blocks = 2 blocks/CU.
__global__ __launch_bounds__(256)
void gemm_out(const unsigned short* __restrict__ X, const unsigned short* __restrict__ W,
              const float* __restrict__ bias, float* __restrict__ dst)
{
    __shared__ __align__(16) unsigned short As[128 * 32];
    __shared__ __align__(16) unsigned short Bs[64 * 32];
    const int tid  = threadIdx.x;
    const int m0   = blockIdx.y * 128;
    const int n0   = blockIdx.x * 64;
    const int lane = tid & 63;
    const int w    = tid >> 6;
    const int wm   = (w >> 1) * 64, wn = (w & 1) * 32;
    const int lr   = lane & 15;
    const int lg   = lane >> 4;

    f32x4 acc[4][2];
#pragma unroll
    for (int i = 0; i < 4; i++)
#pragma unroll
        for (int j = 0; j < 2; j++) acc[i][j] = f32x4{0.f, 0.f, 0.f, 0.f};

    for (int k0 = 0; k0 < DM; k0 += 32) {
        __syncthreads();
#pragma unroll
        for (int j = 0; j < 2; j++) {
            int e = tid + j * 256;
            int row = e >> 2, c8 = (e & 3) * 8;
            __builtin_amdgcn_global_load_lds(
                (const __attribute__((address_space(1))) unsigned*)&X[(size_t)(m0 + row) * DM + k0 + c8],
                (__attribute__((address_space(3))) unsigned*)&As[e * 8], 16, 0, 0);
        }
        {
            int row = tid >> 2, c8 = (tid & 3) * 8;
            __builtin_amdgcn_global_load_lds(
                (const __attribute__((address_space(1))) unsigned*)&W[(size_t)(n0 + row) * DM + k0 + c8],
                (__attribute__((address_space(3))) unsigned*)&Bs[tid * 8], 16, 0, 0);
        }
        __syncthreads();
        bf16x8 af[4], bfr[2];
#pragma unroll
        for (int mi = 0; mi < 4; mi++)
            af[mi] = *(const bf16x8*)(&As[(wm + mi * 16 + lr) * 32 + lg * 8]);
#pragma unroll
        for (int ni = 0; ni < 2; ni++)
            bfr[ni] = *(const bf16x8*)(&Bs[(wn + ni * 16 + lr) * 32 + lg * 8]);
#pragma unroll
        for (int mi = 0; mi < 4; mi++)
#pragma unroll
            for (int ni = 0; ni < 2; ni++)
                acc[mi][ni] = __builtin_amdgcn_mfma_f32_16x16x32_bf16(
                    af[mi], bfr[ni], acc[mi][ni], 0, 0, 0);
    }
#pragma unroll
    for (int mi = 0; mi < 4; mi++)
#pragma unroll
        for (int ni = 0; ni < 2; ni++) {
            const int gcol = n0 + wn + ni * 16 + lr;
            const float bv = bias[gcol];
            const int grow0 = m0 + wm + mi * 16 + lg * 4;
#pragma unroll
            for (int r = 0; r < 4; r++)
                dst[(size_t)(grow0 + r) * DM + gcol] = acc[mi][ni][r] + bv;
        }
}

// Flash attention v3 (transposed): S^T = K*Q^T so softmax rows live along
// lanes (col=lr=q). Mask: 1 uint2/lane/iter. P stored [q][kv] packed 8B.
// O^T = V^T * P^T; output packed 8B stores. Grid 1024 (XCD swizzle), 4 waves.
__global__ __launch_bounds__(256, 4)
void attn(const unsigned short* __restrict__ q_ws,
          const unsigned short* __restrict__ k_ws,
          const unsigned short* __restrict__ vt_ws,
          const unsigned* __restrict__ mbits,
          unsigned short* __restrict__ ctx)
{
    __shared__ __align__(16) unsigned short Ks[64 * 72];  // [kv][dh], +8 pad
    __shared__ __align__(16) unsigned short Vs[64 * 72];  // [dh][kv], +8 pad
    __shared__ __align__(16) unsigned short Pq[4][16 * 72]; // per-wave P [q][kv]
    const int tid = threadIdx.x, lane = tid & 63, w = tid >> 6;
    const int lr = lane & 15, lg = lane >> 4;

    const int i    = blockIdx.x;            // 0..1023
    const int xcd  = i & 7;
    const int slot = i >> 3;                // 0..127
    const int bh   = xcd * 4 + (slot >> 5); // 4 bh per XCD
    const int qblk = slot & 31;
    const int b  = bh >> 4;
    const int h  = bh & 15;
    const int q0 = qblk * 64 + w * 16;
    const int qrow = q0 + lr;               // this lane's q row

    const int srow = tid >> 3;   // staging row
    const int sseg = tid & 7;    // 16B segment

    const unsigned short* qh = q_ws + (size_t)bh * S_LEN * DH;
    const unsigned short* kh = k_ws + (size_t)bh * S_LEN * DH;
    const unsigned short* vh = vt_ws + (size_t)bh * DH * S_LEN;
    const unsigned* mrow = mbits + (size_t)(b * S_LEN + qrow) * (S_LEN / 32);

    // Q fragment: Q[q=lr][dh-chunk lg] — used as the B operand of K*Q^T.
    bf16x8 aq[2];
#pragma unroll
    for (int c = 0; c < 2; c++)
        aq[c] = *(const bf16x8*)(&qh[(size_t)qrow * DH + c * 32 + lg * 8]);

    f32x4 acc[4];
#pragma unroll
    for (int di = 0; di < 4; di++) acc[di] = f32x4{0.f, 0.f, 0.f, 0.f};
    float rs = 0.f;

    uint4 kreg0, kreg1, vreg0, vreg1;
    kreg0 = *(const uint4*)(&kh[(size_t)(srow)      * DH + sseg * 8]);
    kreg1 = *(const uint4*)(&kh[(size_t)(srow + 32) * DH + sseg * 8]);
    vreg0 = *(const uint4*)(&vh[(size_t)(srow)      * S_LEN + sseg * 8]);
    vreg1 = *(const uint4*)(&vh[(size_t)(srow + 32) * S_LEN + sseg * 8]);

    for (int it = 0; it < 32; it++) {
        const int kv0 = it * 64;
        __syncthreads();
        *(uint4*)(&Ks[(srow)      * 72 + sseg * 8]) = kreg0;
        *(uint4*)(&Ks[(srow + 32) * 72 + sseg * 8]) = kreg1;
        *(uint4*)(&Vs[(srow)      * 72 + sseg * 8]) = vreg0;
        *(uint4*)(&Vs[(srow + 32) * 72 + sseg * 8]) = vreg1;
        __syncthreads();
        if (it < 31) {
            const int kn = kv0 + 64;
            kreg0 = *(const uint4*)(&kh[(size_t)(kn + srow)      * DH + sseg * 8]);
            kreg1 = *(const uint4*)(&kh[(size_t)(kn + srow + 32) * DH + sseg * 8]);
            vreg0 = *(const uint4*)(&vh[(size_t)(srow)      * S_LEN + kn + sseg * 8]);
            vreg1 = *(const uint4*)(&vh[(size_t)(srow + 32) * S_LEN + kn + sseg * 8]);
        }

        const uint2 mw = *(const uint2*)(&mrow[kv0 >> 5]);

        // S^T tiles: D[row=kv_loc=lg*4+r][col=q=lr], kv = kv0+ni*16+lg*4+r.
        f32x4 sf[4];
#pragma unroll
        for (int ni = 0; ni < 4; ni++) {
            bf16x8 ak0 = *(const bf16x8*)(&Ks[(ni * 16 + lr) * 72 + lg * 8]);
            bf16x8 ak1 = *(const bf16x8*)(&Ks[(ni * 16 + lr) * 72 + 32 + lg * 8]);
            f32x4 t = __builtin_amdgcn_mfma_f32_16x16x32_bf16(ak0, aq[0], f32x4{0.f,0.f,0.f,0.f}, 0,0,0);
            t = __builtin_amdgcn_mfma_f32_16x16x32_bf16(ak1, aq[1], t, 0,0,0);
            sf[ni] = t;
        }
#pragma unroll
        for (int ni = 0; ni < 4; ni++)
#pragma unroll
            for (int r = 0; r < 4; r++) {
                unsigned word = (ni & 2) ? mw.y : mw.x;
                unsigned bit = (word >> ((ni & 1) * 16 + lg * 4 + r)) & 1u;
                float t = sf[ni][r] * 0.125f + (bit ? -1e5f : -8.0f);
                float p = __expf(fminf(t, 60.f));
                sf[ni][r] = p;
                rs += p;
            }

        // P[q=lr][kv]: r-values contiguous -> packed 8B writes, 4 per lane.
        unsigned short* pq = &Pq[w][0];
#pragma unroll
        for (int ni = 0; ni < 4; ni++) {
            unsigned lo = (unsigned)f2bf(sf[ni][0]) | ((unsigned)f2bf(sf[ni][1]) << 16);
            unsigned hi = (unsigned)f2bf(sf[ni][2]) | ((unsigned)f2bf(sf[ni][3]) << 16);
            *(uint2*)(&pq[lr * 72 + ni * 16 + lg * 4]) = uint2{lo, hi};
        }

        // B-frags of P^T: lane needs P[q=lr][kv = c*32 + lg*8 + j].
        bf16x8 bp0 = *(const bf16x8*)(&pq[lr * 72 + lg * 8]);
        bf16x8 bp1 = *(const bf16x8*)(&pq[lr * 72 + 32 + lg * 8]);
#pragma unroll
        for (int di = 0; di < 4; di++) {
            bf16x8 av0 = *(const bf16x8*)(&Vs[(di * 16 + lr) * 72 + lg * 8]);
            bf16x8 av1 = *(const bf16x8*)(&Vs[(di * 16 + lr) * 72 + 32 + lg * 8]);
            acc[di] = __builtin_amdgcn_mfma_f32_16x16x32_bf16(av0, bp0, acc[di], 0, 0, 0);
            acc[di] = __builtin_amdgcn_mfma_f32_16x16x32_bf16(av1, bp1, acc[di], 0, 0, 0);
        }
    }

    // Row sum for q=lr lives split across lg groups: reduce, normalize, store.
    rs += __shfl_xor(rs, 16);
    rs += __shfl_xor(rs, 32);
    const float inv = 1.0f / fmaxf(rs, 1e-37f);

    // acc[di] = O^T[dh=di*16+lg*4+r][q=lr] -> ctx[b*S+q][h*64+dh], packed 8B.
    unsigned short* crow = &ctx[((size_t)(b * S_LEN + qrow)) * DM + h * DH];
#pragma unroll
    for (int di = 0; di < 4; di++) {
        unsigned lo = (unsigned)f2bf(acc[di][0] * inv) | ((unsigned)f2bf(acc[di][1] * inv) << 16);
        unsigned hi = (unsigned)f2bf(acc[di][2] * inv) | ((unsigned)f2bf(acc[di][3] * inv) << 16);
        *(uint2*)(&crow[di * 16 + lg * 4]) = uint2{lo, hi};
    }
}

extern "C" void kernel_launch(void* const* d_in, const int* in_sizes, int n_in,
                              void* d_out, int out_size, void* d_ws, size_t ws_size,
                              hipStream_t stream)
{
    (void)in_sizes; (void)n_in; (void)out_size; (void)ws_size;
    const float* Q  = (const float*)d_in[0];
    const float* K  = (const float*)d_in[1];
    const float* V  = (const float*)d_in[2];
    const int*   Mk = (const int*)d_in[3];
    const float* Wq = (const float*)d_in[4];
    const float* bq = (const float*)d_in[5];
    const float* Wk = (const float*)d_in[6];
    const float* bk = (const float*)d_in[7];
    const float* Wv = (const float*)d_in[8];
    const float* bv = (const float*)d_in[9];
    const float* Wo = (const float*)d_in[10];
    const float* bo = (const float*)d_in[11];

    const int NX = MROWS * DM;   // 4194304
    const int NW = DM * DM;      // 1048576

    unsigned short* q_ws  = (unsigned short*)d_ws;
    unsigned short* k_ws  = q_ws + (size_t)NX;
    unsigned short* vt_ws = k_ws + (size_t)NX;
    unsigned short* ctx   = vt_ws + (size_t)NX;
    unsigned*       mbits = (unsigned*)(ctx + (size_t)NX);
    unsigned short* Wbq   = (unsigned short*)(mbits + (size_t)MROWS * (S_LEN / 32));
    unsigned short* Wbk   = Wbq + (size_t)NW;
    unsigned short* Wbv   = Wbk + (size_t)NW;
    unsigned short* Wbo   = Wbv + (size_t)NW;
    unsigned short* Xbq   = Wbo + (size_t)NW;
    unsigned short* Xbk   = Xbq + (size_t)NX;
    unsigned short* Xbv   = Xbk + (size_t)NX;
    float* out = (float*)d_out;

    dim3 blk(256);
    prep<<<dim3(9216), blk, 0, stream>>>(Mk, mbits, Q, Xbq, K, Xbk, V, Xbv,
                                         Wq, Wbq, Wk, Wbk, Wv, Wbv, Wo, Wbo);

    gemm128<<<dim3(8, 32, 3), blk, 0, stream>>>(Xbq, Xbk, Xbv, Wbq, Wbk, Wbv,
                                                bq, bk, bv, q_ws, k_ws, vt_ws);

    attn<<<dim3(1024), blk, 0, stream>>>(q_ws, k_ws, vt_ws, mbits, ctx);

    gemm_out<<<dim3(16, 32), blk, 0, stream>>>(ctx, Wbo, bo, out);
}